// Round 1
// baseline (1100.575 us; speedup 1.0000x reference)
//
#include <hip/hip_runtime.h>
#include <hip/hip_bf16.h>

// Row-gather: out[token, 0:ple_dim] = table[ids[token], start : start+ple_dim]
// start = layer_idx * ple_dim; table row stride = hidden floats.
//
// v2: two consecutive float4's per thread (32 B/lane). A 64-lane wave covers
// 128 float4's = 2 full tokens (ple_dim=256 -> 64 float4/token), so a
// float4-pair never straddles a token boundary (pair index is even, token
// boundary at multiples of 64). This halves wave count, doubles per-thread
// MLP (two independent dwordx4 loads in flight), and loads the token id once
// per pair instead of once per float4.

__global__ __launch_bounds__(256) void ple_gather_kernel(
    const int* __restrict__ ids,          // [n_tokens]
    const float* __restrict__ table,      // [VOCAB, hidden]
    const int* __restrict__ layer_idx_p,  // device scalar
    float* __restrict__ out,              // [n_tokens, ple_dim]
    int n_tokens,
    int hidden,
    int ple_dim,
    int vpt_log2,          // log2(ple_dim/4)
    int total_vec)         // n_tokens * (ple_dim/4)
{
    const int pair = blockIdx.x * blockDim.x + threadIdx.x;
    const int i0   = pair << 1;                    // first float4 index
    if (i0 >= total_vec) return;

    const int start = layer_idx_p[0] * ple_dim;    // uniform -> s_load

    const int token = i0 >> vpt_log2;              // pair never straddles token
    const int col4  = i0 & ((1 << vpt_log2) - 1);

    const int id = ids[token];
    const float4* __restrict__ src =
        (const float4*)(table + (size_t)id * (size_t)hidden + start) + col4;
    float4* __restrict__ dst = (float4*)out + i0;

    // Two independent 16B loads issued back-to-back, then two 16B stores.
    float4 a = src[0];
    float4 b = src[1];
    dst[0] = a;
    dst[1] = b;
}

extern "C" void kernel_launch(void* const* d_in, const int* in_sizes, int n_in,
                              void* d_out, int out_size, void* d_ws, size_t ws_size,
                              hipStream_t stream) {
    const int*   ids       = (const int*)d_in[0];
    const float* table     = (const float*)d_in[1];
    const int*   layer_idx = (const int*)d_in[2];

    const int n_tokens = in_sizes[0];                 // B*S = 16384
    const int ple_dim  = out_size / n_tokens;         // 256
    const int hidden   = 2048;                        // reference HIDDEN (row stride)

    const int vec_per_token = ple_dim / 4;            // 64
    const int vpt_log2      = __builtin_ctz(vec_per_token);
    const int total_vec     = n_tokens * vec_per_token;  // 1,048,576

    const int block = 256;
    const int pairs = total_vec / 2;                  // 524,288 threads
    const int grid  = (pairs + block - 1) / block;    // 2048 blocks

    ple_gather_kernel<<<grid, block, 0, stream>>>(
        ids, table, layer_idx, (float*)d_out,
        n_tokens, hidden, ple_dim, vpt_log2, total_vec);
}